// Round 8
// baseline (432.656 us; speedup 1.0000x reference)
//
#include <hip/hip_runtime.h>
#include <math.h>

typedef float v2f __attribute__((ext_vector_type(2)));

#define TILE 32
#define HALO 5
#define IN_T 42              // TILE + 2*HALO rows/cols
#define ROWP 42              // staged pairs per row; 84 words/row ≡ 20 (mod 32) -> ≤2-way banks
#define SINT_P 33            // float4 pitch of s_int (32 + 1 pad -> row stride ≡ 4 mod 32)
#define HWDIM 512
#define NPLANES 48           // B*C
#define NBLK (16*16*48)      // 12288 blocks
#define NPIX (16ull*3ull*512ull*512ull)

struct GW { float g[11]; };

__global__ __launch_bounds__(256, 4) void ssim_main(
    const float* __restrict__ img1, const float* __restrict__ img2,
    float* __restrict__ wsum, unsigned* __restrict__ wcnt,
    float* __restrict__ out, GW gw)
{
    __shared__ alignas(16) v2f sxy[IN_T][ROWP];        // (x,y) per pixel
    __shared__ alignas(16) float4 s_int[IN_T][SINT_P]; // (Xh, Yh, UUh, VVh)
    __shared__ float s_red[4];

    const int tid = threadIdx.x;
    const int tx = blockIdx.x, ty = blockIdx.y, plane = blockIdx.z;
    const float* __restrict__ p1 = img1 + (size_t)plane * (HWDIM * HWDIM);
    const float* __restrict__ p2 = img2 + (size_t)plane * (HWDIM * HWDIM);
    const int gy0 = ty * TILE - HALO;
    const int gx0 = tx * TILE - HALO;

    // ---- stage interleaved (x,y) pairs, zero-padded at image borders ----
    for (int idx = tid; idx < IN_T * ROWP; idx += 256) {
        const int r = idx / ROWP;
        const int c = idx - r * ROWP;
        const int gy = gy0 + r, gx = gx0 + c;
        float a = 0.0f, b = 0.0f;
        if (gy >= 0 && gy < HWDIM && gx >= 0 && gx < HWDIM) {
            const int off = gy * HWDIM + gx;
            a = p1[off];
            b = p2[off];
        }
        v2f pr; pr.x = a; pr.y = b;
        sxy[r][c] = pr;
    }
    __syncthreads();

    // ---- horizontal 11-tap pass (row-fast item map -> ≤2-way banks) ----
    // quantities as pairs: A = (x, y), B = ((x+y)^2, (x-y)^2)
    for (int item = tid; item < IN_T * 8; item += 256) {
        const int g8 = item / IN_T;        // 0..7   (slow)
        const int r  = item - g8 * IN_T;   // 0..41  (fast within wave)
        const int c0 = g8 * 4;             // output col base

        v2f xy[14];
#pragma unroll
        for (int j = 0; j < 7; ++j) {
            const float4 f = *reinterpret_cast<const float4*>(&sxy[r][c0 + 2 * j]);
            v2f t0; t0.x = f.x; t0.y = f.y;
            v2f t1; t1.x = f.z; t1.y = f.w;
            xy[2 * j]     = t0;
            xy[2 * j + 1] = t1;
        }

        v2f accA[4], accB[4];
#pragma unroll
        for (int o = 0; o < 4; ++o) { accA[o] = 0.0f; accB[o] = 0.0f; }

#pragma unroll
        for (int e = 0; e < 14; ++e) {
            const v2f p = xy[e];
            const float u = p.x + p.y;
            const float w = p.x - p.y;
            v2f uv; uv.x = u; uv.y = w;
            const v2f qq = uv * uv;
#pragma unroll
            for (int o = 0; o < 4; ++o) {
                const int k = e - o;
                if (k >= 0 && k < 11) {
                    v2f gg; gg.x = gw.g[k]; gg.y = gw.g[k];
                    accA[o] = __builtin_elementwise_fma(gg, p,  accA[o]);
                    accB[o] = __builtin_elementwise_fma(gg, qq, accB[o]);
                }
            }
        }
#pragma unroll
        for (int o = 0; o < 4; ++o)
            s_int[r][c0 + o] = make_float4(accA[o].x, accA[o].y, accB[o].x, accB[o].y);
    }
    __syncthreads();

    // ---- vertical 11-tap pass: thread = (col, 4 output rows), sliding window ----
    const int c  = tid & 31;
    const int r0 = (tid >> 5) * 4;         // 0,4,...,28
    v2f vA[4], vB[4];
#pragma unroll
    for (int o = 0; o < 4; ++o) { vA[o] = 0.0f; vB[o] = 0.0f; }

#pragma unroll
    for (int j = 0; j < 14; ++j) {
        const float4 f = s_int[r0 + j][c];
        v2f A; A.x = f.x; A.y = f.y;
        v2f B; B.x = f.z; B.y = f.w;
#pragma unroll
        for (int o = 0; o < 4; ++o) {
            const int k = j - o;
            if (k >= 0 && k < 11) {
                v2f gg; gg.x = gw.g[k]; gg.y = gw.g[k];
                vA[o] = __builtin_elementwise_fma(gg, A, vA[o]);
                vB[o] = __builtin_elementwise_fma(gg, B, vB[o]);
            }
        }
    }

    // ---- SSIM map + local sum ----
    const float C1 = 0.01f * 0.01f;
    const float C2 = 0.03f * 0.03f;
    float lsum = 0.0f;
#pragma unroll
    for (int o = 0; o < 4; ++o) {
        const float mu1 = vA[o].x;
        const float mu2 = vA[o].y;
        const float s_uu = vB[o].x;
        const float s_vv = vB[o].y;
        const float mu1_sq = mu1 * mu1;
        const float mu2_sq = mu2 * mu2;
        const float mu1_mu2 = mu1 * mu2;
        const float sigma12 = (s_uu - s_vv) * 0.25f - mu1_mu2;
        const float sigsum  = (s_uu + s_vv) * 0.5f - mu1_sq - mu2_sq;
        const float num = (2.0f * mu1_mu2 + C1) * (2.0f * sigma12 + C2);
        const float den = (mu1_sq + mu2_sq + C1) * (sigsum + C2);
        lsum += num / den;
    }

    // ---- block reduce -> device atomic -> last block finalizes ----
#pragma unroll
    for (int off = 32; off > 0; off >>= 1) lsum += __shfl_down(lsum, off, 64);
    if ((tid & 63) == 0) s_red[tid >> 6] = lsum;
    __syncthreads();
    if (tid == 0) {
        const float part = s_red[0] + s_red[1] + s_red[2] + s_red[3];
        // ws poison 0xAAAAAAAA as float = -3.03e-13: negligible addend, no init needed
        atomicAdd(wsum, part);
        __threadfence();
        const unsigned old = atomicAdd(wcnt, 1u);
        // counter may start at 0xAAAAAAAA (poison) or 0 (zeroed) — accept both
        if (old == 0xAAAAAAAAu + (unsigned)(NBLK - 1) || old == (unsigned)(NBLK - 1)) {
            __threadfence();
            const float s = atomicAdd(wsum, 0.0f);   // coherent device-scope read
            out[0] = 1.0f - s * (1.0f / (float)NPIX);
        }
    }
}

extern "C" void kernel_launch(void* const* d_in, const int* in_sizes, int n_in,
                              void* d_out, int out_size, void* d_ws, size_t ws_size,
                              hipStream_t stream) {
    const float* img1 = (const float*)d_in[0];
    const float* img2 = (const float*)d_in[1];
    float* out = (float*)d_out;
    float* wsum = (float*)d_ws;
    unsigned* wcnt = ((unsigned*)d_ws) + 1;

    // Gaussian window, computed exactly as the reference (float64 -> float32)
    GW gw;
    {
        double g[11], s = 0.0;
        for (int i = 0; i < 11; ++i) {
            const double d = (double)(i - 5);
            g[i] = exp(-(d * d) / (2.0 * 1.5 * 1.5));
            s += g[i];
        }
        for (int i = 0; i < 11; ++i) gw.g[i] = (float)(g[i] / s);
    }

    dim3 grid(HWDIM / TILE, HWDIM / TILE, NPLANES);   // 16 x 16 x 48 = 12288
    ssim_main<<<grid, 256, 0, stream>>>(img1, img2, wsum, wcnt, out, gw);
}

// Round 9
// 181.834 us; speedup vs baseline: 2.3794x; 2.3794x over previous
//
#include <hip/hip_runtime.h>
#include <math.h>

typedef float v2f __attribute__((ext_vector_type(2)));

#define TILE 32
#define HALO 5
#define IN_T 42              // TILE + 2*HALO rows/cols
#define ROWP 42              // staged pairs per row; 84 words/row ≡ 20 (mod 32) -> ≤2-way banks
#define SINT_P 33            // float4 pitch of s_int (32 + 1 pad -> row stride ≡ 4 mod 32)
#define HWDIM 512
#define NPLANES 48           // B*C
#define NBLK (16*16*48)      // 12288 blocks
#define NPIX (16ull*3ull*512ull*512ull)

struct GW { float g[11]; };

// ---------------- final reduce: 12288 partials -> 1 - mean ----------------
__global__ __launch_bounds__(256) void ssim_reduce(
    const float* __restrict__ partial, float* __restrict__ out)
{
    __shared__ float s_red[4];
    const int tid = threadIdx.x;
    float s = 0.0f;
#pragma unroll
    for (int k = 0; k < NBLK / 256; ++k) s += partial[tid + k * 256];
#pragma unroll
    for (int off = 32; off > 0; off >>= 1) s += __shfl_down(s, off, 64);
    if ((tid & 63) == 0) s_red[tid >> 6] = s;
    __syncthreads();
    if (tid == 0) {
        const float tot = s_red[0] + s_red[1] + s_red[2] + s_red[3];
        out[0] = 1.0f - tot * (1.0f / (float)NPIX);
    }
}

// ---------------- main fused SSIM kernel ----------------
__global__ __launch_bounds__(256, 4) void ssim_main(
    const float* __restrict__ img1, const float* __restrict__ img2,
    float* __restrict__ partial, GW gw)
{
    __shared__ alignas(16) v2f sxy[IN_T][ROWP];        // (x,y) per pixel
    __shared__ alignas(16) float4 s_int[IN_T][SINT_P]; // (Xh, Yh, UUh, VVh)
    __shared__ float s_red[4];

    const int tid = threadIdx.x;
    const int tx = blockIdx.x, ty = blockIdx.y, plane = blockIdx.z;
    const float* __restrict__ p1 = img1 + (size_t)plane * (HWDIM * HWDIM);
    const float* __restrict__ p2 = img2 + (size_t)plane * (HWDIM * HWDIM);
    const int gy0 = ty * TILE - HALO;
    const int gx0 = tx * TILE - HALO;

    // ---- stage interleaved (x,y) pairs, zero-padded at image borders ----
    for (int idx = tid; idx < IN_T * ROWP; idx += 256) {
        const int r = idx / ROWP;
        const int c = idx - r * ROWP;
        const int gy = gy0 + r, gx = gx0 + c;
        float a = 0.0f, b = 0.0f;
        if (gy >= 0 && gy < HWDIM && gx >= 0 && gx < HWDIM) {
            const int off = gy * HWDIM + gx;
            a = p1[off];
            b = p2[off];
        }
        v2f pr; pr.x = a; pr.y = b;
        sxy[r][c] = pr;
    }
    __syncthreads();

    // ---- horizontal 11-tap pass (row-fast item map -> ≤2-way banks) ----
    // quantities as pairs: A = (x, y), B = ((x+y)^2, (x-y)^2)
    for (int item = tid; item < IN_T * 8; item += 256) {
        const int g8 = item / IN_T;        // 0..7   (slow)
        const int r  = item - g8 * IN_T;   // 0..41  (fast within wave)
        const int c0 = g8 * 4;             // output col base

        v2f xy[14];
#pragma unroll
        for (int j = 0; j < 7; ++j) {
            const float4 f = *reinterpret_cast<const float4*>(&sxy[r][c0 + 2 * j]);
            v2f t0; t0.x = f.x; t0.y = f.y;
            v2f t1; t1.x = f.z; t1.y = f.w;
            xy[2 * j]     = t0;
            xy[2 * j + 1] = t1;
        }

        v2f accA[4], accB[4];
#pragma unroll
        for (int o = 0; o < 4; ++o) { accA[o] = 0.0f; accB[o] = 0.0f; }

#pragma unroll
        for (int e = 0; e < 14; ++e) {
            const v2f p = xy[e];
            const float u = p.x + p.y;
            const float w = p.x - p.y;
            v2f uv; uv.x = u; uv.y = w;
            const v2f qq = uv * uv;
#pragma unroll
            for (int o = 0; o < 4; ++o) {
                const int k = e - o;
                if (k >= 0 && k < 11) {
                    v2f gg; gg.x = gw.g[k]; gg.y = gw.g[k];
                    accA[o] = __builtin_elementwise_fma(gg, p,  accA[o]);
                    accB[o] = __builtin_elementwise_fma(gg, qq, accB[o]);
                }
            }
        }
#pragma unroll
        for (int o = 0; o < 4; ++o)
            s_int[r][c0 + o] = make_float4(accA[o].x, accA[o].y, accB[o].x, accB[o].y);
    }
    __syncthreads();

    // ---- vertical 11-tap pass: thread = (col, 4 output rows), sliding window ----
    const int c  = tid & 31;
    const int r0 = (tid >> 5) * 4;         // 0,4,...,28
    v2f vA[4], vB[4];
#pragma unroll
    for (int o = 0; o < 4; ++o) { vA[o] = 0.0f; vB[o] = 0.0f; }

#pragma unroll
    for (int j = 0; j < 14; ++j) {
        const float4 f = s_int[r0 + j][c];
        v2f A; A.x = f.x; A.y = f.y;
        v2f B; B.x = f.z; B.y = f.w;
#pragma unroll
        for (int o = 0; o < 4; ++o) {
            const int k = j - o;
            if (k >= 0 && k < 11) {
                v2f gg; gg.x = gw.g[k]; gg.y = gw.g[k];
                vA[o] = __builtin_elementwise_fma(gg, A, vA[o]);
                vB[o] = __builtin_elementwise_fma(gg, B, vB[o]);
            }
        }
    }

    // ---- SSIM map + local sum ----
    const float C1 = 0.01f * 0.01f;
    const float C2 = 0.03f * 0.03f;
    float lsum = 0.0f;
#pragma unroll
    for (int o = 0; o < 4; ++o) {
        const float mu1 = vA[o].x;
        const float mu2 = vA[o].y;
        const float s_uu = vB[o].x;
        const float s_vv = vB[o].y;
        const float mu1_sq = mu1 * mu1;
        const float mu2_sq = mu2 * mu2;
        const float mu1_mu2 = mu1 * mu2;
        const float sigma12 = (s_uu - s_vv) * 0.25f - mu1_mu2;
        const float sigsum  = (s_uu + s_vv) * 0.5f - mu1_sq - mu2_sq;
        const float num = (2.0f * mu1_mu2 + C1) * (2.0f * sigma12 + C2);
        const float den = (mu1_sq + mu2_sq + C1) * (sigsum + C2);
        lsum += num / den;
    }

    // ---- block reduce -> one plain store per block (no atomics) ----
#pragma unroll
    for (int off = 32; off > 0; off >>= 1) lsum += __shfl_down(lsum, off, 64);
    if ((tid & 63) == 0) s_red[tid >> 6] = lsum;
    __syncthreads();
    if (tid == 0) {
        const int bid = (blockIdx.z * gridDim.y + blockIdx.y) * gridDim.x + blockIdx.x;
        partial[bid] = s_red[0] + s_red[1] + s_red[2] + s_red[3];
    }
}

extern "C" void kernel_launch(void* const* d_in, const int* in_sizes, int n_in,
                              void* d_out, int out_size, void* d_ws, size_t ws_size,
                              hipStream_t stream) {
    const float* img1 = (const float*)d_in[0];
    const float* img2 = (const float*)d_in[1];
    float* out = (float*)d_out;
    float* wsf = (float*)d_ws;   // 12288 partial sums (every slot written every launch)

    // Gaussian window, computed exactly as the reference (float64 -> float32)
    GW gw;
    {
        double g[11], s = 0.0;
        for (int i = 0; i < 11; ++i) {
            const double d = (double)(i - 5);
            g[i] = exp(-(d * d) / (2.0 * 1.5 * 1.5));
            s += g[i];
        }
        for (int i = 0; i < 11; ++i) gw.g[i] = (float)(g[i] / s);
    }

    dim3 grid(HWDIM / TILE, HWDIM / TILE, NPLANES);   // 16 x 16 x 48 = 12288
    ssim_main<<<grid, 256, 0, stream>>>(img1, img2, wsf, gw);
    ssim_reduce<<<1, 256, 0, stream>>>(wsf, out);
}